// Round 12
// baseline (992.463 us; speedup 1.0000x reference)
//
#include <hip/hip_runtime.h>
#include <hip/hip_bf16.h>

// GCN_5016521802361: 2x SAGEConv(aggr='lstm', project=True), N=50000, D=16, F=128, C=40.
// Round 12: Y-free lstm with REGISTER-direct xp B-fragments. Each lane loads its
// MFMA B-frag straight from xp (16B contiguous, global_load_dwordx4; all 8 waves
// read the same 16 rows -> L1 hits), prefetched one step ahead in a parity pair.
// No LDS stage, no DMA, no vmcnt barriers: LDS holds only hb + srcl; the step
// barrier is lgkm-only. G = Wih*xp_s^T + Whh*h^T + bias per step (32 MFMA/wave).

typedef __hip_bfloat16 bf16;
typedef __attribute__((ext_vector_type(8))) short short8;
typedef __attribute__((ext_vector_type(4))) short short4v;
typedef __attribute__((ext_vector_type(4))) float floatx4;

__device__ __forceinline__ float bf2f(bf16 v) { return __bfloat162float(v); }
__device__ __forceinline__ bf16  f2bf(float v) { return __float2bfloat16(v); }
__device__ __forceinline__ float bfs2f(short s) {
    union { float f; unsigned u; } v; v.u = ((unsigned)(unsigned short)s) << 16; return v.f;
}
__device__ __forceinline__ short f2bfs(float v) {
    bf16 b = __float2bfloat16(v); return *(short*)&b;
}

// merged-rcp LSTM cell update (r6, absmax-neutral)
__device__ __forceinline__ float cell(float i_, float f_, float g_, float o_, float& c) {
    float ei = __expf(-i_), ef = __expf(-f_), eg = __expf(2.f * g_);
    float cn = c * __builtin_amdgcn_rcpf(1.f + ef)
             + (eg - 1.f) * __builtin_amdgcn_rcpf((1.f + ei) * (eg + 1.f));
    c = cn;
    float ec = __expf(2.f * cn), eo = __expf(-o_);
    return (ec - 1.f) * __builtin_amdgcn_rcpf((ec + 1.f) * (1.f + eo));
}

// barrier that does NOT drain vmcnt (LDS-only ordering) — in-flight global loads survive
__device__ __forceinline__ void sync_lds_only() {
    asm volatile("s_waitcnt lgkmcnt(0)\n\ts_barrier" ::: "memory");
}

__global__ void detect_dtype(const unsigned short* __restrict__ xb, int* __restrict__ flag) {
    int cnt = 0;
    for (int i = threadIdx.x; i < 1024; i += 64) {
        int e = (xb[i] >> 7) & 0xFF;
        cnt += (e >= 0xC8);
    }
#pragma unroll
    for (int off = 32; off; off >>= 1) cnt += __shfl_down(cnt, off);
    if (threadIdx.x == 0) *flag = (cnt >= 16) ? 1 : 0;   // 1 => inputs are float32
}

struct Cvt { const void* src; bf16* dst; int n; };
struct CvtAll { Cvt t[19]; };

__global__ void convert_inputs(CvtAll ca, const int* __restrict__ flag) {
    const bool isf32 = (*flag != 0);
    const int stride = gridDim.x * blockDim.x;
    const int tid0 = blockIdx.x * blockDim.x + threadIdx.x;
#pragma unroll 1
    for (int k = 0; k < 19; k++) {
        const int n = ca.t[k].n;
        const float* sf = (const float*)ca.t[k].src;
        const bf16*  sb = (const bf16*)ca.t[k].src;
        bf16* d = ca.t[k].dst;
        for (int i = tid0; i < n; i += stride)
            d[i] = isf32 ? f2bf(sf[i]) : sb[i];
    }
}

// generic GEMM (xp writer + final lin2 layer)
template <int NCT, bool RELU, bool BIAS2, bool DUAL, bool OUTF>
__global__ __launch_bounds__(256, 2) void gemm_bias(
    const bf16* __restrict__ A, const bf16* __restrict__ B,
    const bf16* __restrict__ bias, const bf16* __restrict__ bias2,
    const bf16* __restrict__ A2, const bf16* __restrict__ B2,
    void* __restrict__ Cv, const int* __restrict__ oflag,
    int N, int nbt, int ldc)
{
    const int tid = threadIdx.x;
    const int w = tid >> 6, l = tid & 63, q = l >> 4, lid = l & 15;
    const int rowbase = blockIdx.x * 64 + w * 16;
    const int colslice = blockIdx.y * (NCT * 16);

    int arow = rowbase + lid;
    if (arow >= N) arow = N - 1;

    floatx4 acc[NCT];
#pragma unroll
    for (int ct = 0; ct < NCT; ct++) acc[ct] = (floatx4)(0.f);

    short8 bfrag[NCT][4];
#pragma unroll
    for (int ct = 0; ct < NCT; ct++) {
        int j = colslice + ct * 16 + lid;
        if (j >= nbt) j = nbt - 1;
#pragma unroll
        for (int kt = 0; kt < 4; kt++)
            bfrag[ct][kt] = *(const short8*)(B + (size_t)j * 128 + kt * 32 + q * 8);
    }
#pragma unroll
    for (int kt = 0; kt < 4; kt++) {
        short8 af = *(const short8*)(A + (size_t)arow * 128 + kt * 32 + q * 8);
#pragma unroll
        for (int ct = 0; ct < NCT; ct++)
            acc[ct] = __builtin_amdgcn_mfma_f32_16x16x32_bf16(af, bfrag[ct][kt], acc[ct], 0, 0, 0);
    }
    if constexpr (DUAL) {
#pragma unroll
        for (int ct = 0; ct < NCT; ct++) {
            int j = colslice + ct * 16 + lid;
            if (j >= nbt) j = nbt - 1;
#pragma unroll
            for (int kt = 0; kt < 4; kt++)
                bfrag[ct][kt] = *(const short8*)(B2 + (size_t)j * 128 + kt * 32 + q * 8);
        }
#pragma unroll
        for (int kt = 0; kt < 4; kt++) {
            short8 af = *(const short8*)(A2 + (size_t)arow * 128 + kt * 32 + q * 8);
#pragma unroll
            for (int ct = 0; ct < NCT; ct++)
                acc[ct] = __builtin_amdgcn_mfma_f32_16x16x32_bf16(af, bfrag[ct][kt], acc[ct], 0, 0, 0);
        }
    }
    bool of32 = false;
    if constexpr (OUTF) of32 = (*oflag != 0);
#pragma unroll
    for (int ct = 0; ct < NCT; ct++) {
        int cg = colslice + ct * 16 + lid;
        int cb = cg < nbt ? cg : nbt - 1;
        float bv = bf2f(bias[cb]);
        if constexpr (BIAS2) bv += bf2f(bias2[cb]);
#pragma unroll
        for (int r = 0; r < 4; r++) {
            int row = rowbase + q * 4 + r;
            float v = acc[ct][r] + bv;
            if constexpr (RELU) v = fmaxf(v, 0.f);
            if (row < N && cg < nbt) {
                size_t idx = (size_t)row * ldc + cg;
                if constexpr (OUTF) {
                    if (of32) ((float*)Cv)[idx] = v;
                    else      ((bf16*)Cv)[idx] = f2bf(v);
                } else {
                    ((bf16*)Cv)[idx] = f2bf(v);
                }
            }
        }
    }
}

// ---------------------------------------------------------------------------
// Fused between-layers chain: h1 = relu(aggr@Wl^T + bl + X@Wr^T) (global + LDS);
// xp2 = relu(h1@Wp2^T + bp2) (global).
// ---------------------------------------------------------------------------
__global__ __launch_bounds__(256, 2) void fused_lin_xp(
    const bf16* __restrict__ aggr, const bf16* __restrict__ Wl, const bf16* __restrict__ bl,
    const bf16* __restrict__ X, const bf16* __restrict__ Wr,
    bf16* __restrict__ h1out,
    const bf16* __restrict__ Wp2, const bf16* __restrict__ bp2,
    bf16* __restrict__ xp2out, int N)
{
    __shared__ bf16 T1[64][136];
    const int tid = threadIdx.x;
    const int w = tid >> 6, l = tid & 63, q = l >> 4, lid = l & 15;
    const int rowbase = blockIdx.x * 64;

    int arow = rowbase + w * 16 + lid;
    if (arow >= N) arow = N - 1;

    floatx4 acc[8];
    short8 bfrag[8][4];

    // ---- stage A: h1 ----
#pragma unroll
    for (int ct = 0; ct < 8; ct++) acc[ct] = (floatx4)(0.f);
#pragma unroll
    for (int ct = 0; ct < 8; ct++) {
        int j = ct * 16 + lid;
#pragma unroll
        for (int kt = 0; kt < 4; kt++)
            bfrag[ct][kt] = *(const short8*)(Wl + (size_t)j * 128 + kt * 32 + q * 8);
    }
#pragma unroll
    for (int kt = 0; kt < 4; kt++) {
        short8 af = *(const short8*)(aggr + (size_t)arow * 128 + kt * 32 + q * 8);
#pragma unroll
        for (int ct = 0; ct < 8; ct++)
            acc[ct] = __builtin_amdgcn_mfma_f32_16x16x32_bf16(af, bfrag[ct][kt], acc[ct], 0, 0, 0);
    }
#pragma unroll
    for (int ct = 0; ct < 8; ct++) {
        int j = ct * 16 + lid;
#pragma unroll
        for (int kt = 0; kt < 4; kt++)
            bfrag[ct][kt] = *(const short8*)(Wr + (size_t)j * 128 + kt * 32 + q * 8);
    }
#pragma unroll
    for (int kt = 0; kt < 4; kt++) {
        short8 af = *(const short8*)(X + (size_t)arow * 128 + kt * 32 + q * 8);
#pragma unroll
        for (int ct = 0; ct < 8; ct++)
            acc[ct] = __builtin_amdgcn_mfma_f32_16x16x32_bf16(af, bfrag[ct][kt], acc[ct], 0, 0, 0);
    }
#pragma unroll
    for (int ct = 0; ct < 8; ct++) {
        int col = ct * 16 + lid;
        float bv = bf2f(bl[col]);
#pragma unroll
        for (int r = 0; r < 4; r++) {
            int rl = w * 16 + q * 4 + r;
            bf16 hv = f2bf(fmaxf(acc[ct][r] + bv, 0.f));
            T1[rl][col] = hv;
            int row = rowbase + rl;
            if (row < N) h1out[(size_t)row * 128 + col] = hv;
        }
    }
    __syncthreads();

    // ---- stage B: xp2 ----
#pragma unroll
    for (int ct = 0; ct < 8; ct++) {
        int j = ct * 16 + lid;
#pragma unroll
        for (int kt = 0; kt < 4; kt++)
            bfrag[ct][kt] = *(const short8*)(Wp2 + (size_t)j * 128 + kt * 32 + q * 8);
    }
#pragma unroll
    for (int ct = 0; ct < 8; ct++) acc[ct] = (floatx4)(0.f);
#pragma unroll
    for (int kt = 0; kt < 4; kt++) {
        short8 af = *(const short8*)&T1[w * 16 + lid][kt * 32 + q * 8];
#pragma unroll
        for (int ct = 0; ct < 8; ct++)
            acc[ct] = __builtin_amdgcn_mfma_f32_16x16x32_bf16(af, bfrag[ct][kt], acc[ct], 0, 0, 0);
    }
#pragma unroll
    for (int ct = 0; ct < 8; ct++) {
        int col = ct * 16 + lid;
        float bv = bf2f(bp2[col]);
#pragma unroll
        for (int r = 0; r < 4; r++) {
            int row = rowbase + w * 16 + q * 4 + r;
            if (row < N) xp2out[(size_t)row * 128 + col] = f2bf(fmaxf(acc[ct][r] + bv, 0.f));
        }
    }
}

// ---------------------------------------------------------------------------
// LSTM neighbor aggregation, Y-free, register-direct B-frags.
// 512 thr / 8 waves / 16 nodes; wave w owns hidden cols [16w,16w+16).
// Lane (q,lid): B-frag(xp) = xp[srcl[t][lid]][kt*32+q*8 ..+7] — 16B direct load,
// prefetched one step ahead (parity pair, survives the lgkm-only barrier).
// G = Wih*xp_s^T + Whh*h^T + bias; h via hb LDS double-buffer; c in regs.
// ---------------------------------------------------------------------------
__global__ __launch_bounds__(512, 2) void lstm_aggr(
    const bf16* __restrict__ xp,    // [N,128] projected features (L2/L3-resident)
    const int* __restrict__ esrc,   // [N,16]
    const bf16* __restrict__ Wih,   // [512,128]
    const bf16* __restrict__ bih, const bf16* __restrict__ bhh,  // [512]
    const bf16* __restrict__ Whh,   // [512,128]
    bf16* __restrict__ aggr,        // [N,128] out: final h
    int N)
{
    __shared__ alignas(16) bf16 hb[2][16][136];
    __shared__ int srcl[16][16];    // [t][node]

    const int tid = threadIdx.x;
    const int w = tid >> 6, l = tid & 63, q = l >> 4, lid = l & 15;
    const int nodebase = blockIdx.x * 16;   // N = 50000 = 3125*16, exact

    if (tid < 256) {
        int node = tid >> 4, t = tid & 15;
        srcl[t][node] = esrc[(size_t)(nodebase + node) * 16 + t];
    }
    for (int i = tid; i < 16 * 136; i += 512) ((short*)hb[0])[i] = 0;

    // A-fragments: rows gc = g*128 + 16w + lid of Wih and Whh; biases per (g,r)
    short8 wfi[4][4], wfh[4][4];
    float bias[4][4];
#pragma unroll
    for (int g = 0; g < 4; g++) {
        int gc = g * 128 + 16 * w + lid;
#pragma unroll
        for (int kt = 0; kt < 4; kt++) {
            wfi[g][kt] = *(const short8*)(Wih + (size_t)gc * 128 + kt * 32 + q * 8);
            wfh[g][kt] = *(const short8*)(Whh + (size_t)gc * 128 + kt * 32 + q * 8);
        }
#pragma unroll
        for (int r = 0; r < 4; r++) {
            int bc = g * 128 + 16 * w + 4 * q + r;
            bias[g][r] = bf2f(bih[bc]) + bf2f(bhh[bc]);
        }
    }

    float c[4];
#pragma unroll
    for (int r = 0; r < 4; r++) c[r] = 0.f;

    __syncthreads();   // srcl + hb zero visible

    // prefetch B-frags for t=0 into parity slot 0
    short8 bx[2][4];
    {
        int s = srcl[0][lid];
        const bf16* xb = xp + (size_t)s * 128 + q * 8;
#pragma unroll
        for (int kt = 0; kt < 4; kt++)
            bx[0][kt] = *(const short8*)(xb + kt * 32);
    }

#pragma unroll 2
    for (int t = 0; t < 16; t++) {
        const int cb = t & 1, nb = cb ^ 1;

        // prefetch next step's xp B-frags (private regs, survive the lgkm barrier)
        if (t < 15) {
            int s = srcl[t + 1][lid];
            const bf16* xb = xp + (size_t)s * 128 + q * 8;
#pragma unroll
            for (int kt = 0; kt < 4; kt++)
                bx[nb][kt] = *(const short8*)(xb + kt * 32);
        }

        floatx4 acc[4];
#pragma unroll
        for (int g = 0; g < 4; g++)
#pragma unroll
            for (int r = 0; r < 4; r++) acc[g][r] = bias[g][r];

        // G += Wih * xp_s^T + Whh * h^T
#pragma unroll
        for (int kt = 0; kt < 4; kt++) {
            short8 bh = *(const short8*)&hb[cb][lid][kt * 32 + q * 8];
#pragma unroll
            for (int g = 0; g < 4; g++) {
                acc[g] = __builtin_amdgcn_mfma_f32_16x16x32_bf16(wfi[g][kt], bx[cb][kt], acc[g], 0, 0, 0);
                acc[g] = __builtin_amdgcn_mfma_f32_16x16x32_bf16(wfh[g][kt], bh, acc[g], 0, 0, 0);
            }
        }

        // gates; h' cols = 16w + 4q + r for node lid
        {
            short4v hv;
#pragma unroll
            for (int r = 0; r < 4; r++)
                hv[r] = f2bfs(cell(acc[0][r], acc[1][r], acc[2][r], acc[3][r], c[r]));
            if (t < 15) *(short4v*)&hb[nb][lid][16 * w + 4 * q] = hv;
            else        *(short4v*)(aggr + (size_t)(nodebase + lid) * 128 + 16 * w + 4 * q) = hv;
        }

        sync_lds_only();   // orders hb only; xp prefetch stays outstanding
    }
}

extern "C" void kernel_launch(void* const* d_in, const int* in_sizes, int n_in,
                              void* d_out, int out_size, void* d_ws, size_t ws_size,
                              hipStream_t stream)
{
    const int N = 50000;
    const int* es = (const int*)d_in[1];
    char* ws = (char*)d_ws;

    // converted bf16 copies of the 19 used float tensors @[0,15MB)
    static const int idxs[19] = {0, 8,9,10,11,12,13,14,15,16, 17,18,19,20,21,22,23,24,25};
    bf16* conv[19];
    size_t off = 0;
    CvtAll ca;
    for (int k = 0; k < 19; k++) {
        conv[k] = (bf16*)ws + off;
        ca.t[k].src = d_in[idxs[k]];
        ca.t[k].dst = conv[k];
        ca.t[k].n = in_sizes[idxs[k]];
        off += (size_t)((in_sizes[idxs[k]] + 63) & ~63);
    }
    int* flag = (int*)(ws + ((size_t)15 << 20));
    bf16* xp1  = (bf16*)(ws + ((size_t)16 << 20));   // [N,128]
    bf16* aggr = (bf16*)(ws + ((size_t)30 << 20));   // [N,128]
    bf16* xp2  = (bf16*)(ws + ((size_t)44 << 20));   // [N,128]
    bf16* h1   = (bf16*)(ws + ((size_t)58 << 20));   // [N,128]

    const bf16 *xc  = conv[0];
    const bf16 *Wp1 = conv[1],  *bp1 = conv[2],  *Wih1 = conv[3],  *Whh1 = conv[4];
    const bf16 *bih1 = conv[5], *bhh1 = conv[6], *Wl1 = conv[7],   *bl1 = conv[8],  *Wr1 = conv[9];
    const bf16 *Wp2 = conv[10], *bp2 = conv[11], *Wih2 = conv[12], *Whh2 = conv[13];
    const bf16 *bih2 = conv[14], *bhh2 = conv[15], *Wl2 = conv[16], *bl2 = conv[17], *Wr2 = conv[18];

    dim3 blk(256);
    const int gx = (N + 63) / 64;    // 782
    const int gl = N / 16;           // 3125 (exact)

    detect_dtype<<<dim3(1), dim3(64), 0, stream>>>((const unsigned short*)d_in[0], flag);
    convert_inputs<<<dim3(1024), blk, 0, stream>>>(ca, flag);

    // ---- layer 1 ----
    gemm_bias<8, true, false, false, false><<<dim3(gx, 1), blk, 0, stream>>>(
        xc, Wp1, bp1, nullptr, nullptr, nullptr, xp1, nullptr, N, 128, 128);
    lstm_aggr<<<dim3(gl), dim3(512), 0, stream>>>(xp1, es, Wih1, bih1, bhh1, Whh1, aggr, N);

    // ---- between layers: lin1 -> xp2 ----
    fused_lin_xp<<<dim3(gx), blk, 0, stream>>>(
        aggr, Wl1, bl1, xc, Wr1, h1, Wp2, bp2, xp2, N);
    lstm_aggr<<<dim3(gl), dim3(512), 0, stream>>>(xp2, es, Wih2, bih2, bhh2, Whh2, aggr, N);

    // ---- final: out = lin_l2(aggr) + bl2 + lin_r2(h1) ----
    gemm_bias<3, false, false, true, true><<<dim3(gx, 1), blk, 0, stream>>>(
        aggr, Wl2, bl2, nullptr, h1, Wr2, d_out, flag, N, 40, 40);
}

// Round 13
// 754.187 us; speedup vs baseline: 1.3159x; 1.3159x over previous
//
#include <hip/hip_runtime.h>
#include <hip/hip_bf16.h>

// GCN_5016521802361: 2x SAGEConv(aggr='lstm', project=True), N=50000, D=16, F=128, C=40.
// Round 13: revert lstm to the r10 plateau optimum (512 thr, Y-row DMA, 16-node blocks
// — r11/r12's Y-free variants lost: scatter/extra-MFMA cost > gather savings).
// One fix: Y writers now store CONTIGUOUS memory columns (coalesced) and realize the
// lstm permutation by indexing the SOURCE weight row instead (src = decode(jm), read
// once per block from L2-resident weights). Y layout seen by lstm is bit-identical.

typedef __hip_bfloat16 bf16;
typedef __attribute__((ext_vector_type(8))) short short8;
typedef __attribute__((ext_vector_type(4))) short short4v;
typedef __attribute__((ext_vector_type(4))) float floatx4;

__device__ __forceinline__ float bf2f(bf16 v) { return __bfloat162float(v); }
__device__ __forceinline__ bf16  f2bf(float v) { return __float2bfloat16(v); }
__device__ __forceinline__ float bfs2f(short s) {
    union { float f; unsigned u; } v; v.u = ((unsigned)(unsigned short)s) << 16; return v.f;
}
__device__ __forceinline__ short f2bfs(float v) {
    bf16 b = __float2bfloat16(v); return *(short*)&b;
}

// merged-rcp LSTM cell update (r6, absmax-neutral)
__device__ __forceinline__ float cell(float i_, float f_, float g_, float o_, float& c) {
    float ei = __expf(-i_), ef = __expf(-f_), eg = __expf(2.f * g_);
    float cn = c * __builtin_amdgcn_rcpf(1.f + ef)
             + (eg - 1.f) * __builtin_amdgcn_rcpf((1.f + ei) * (eg + 1.f));
    c = cn;
    float ec = __expf(2.f * cn), eo = __expf(-o_);
    return (ec - 1.f) * __builtin_amdgcn_rcpf((ec + 1.f) * (1.f + eo));
}

// Permuted-Y memory position p <-> gate column: p = w*64 + q*16 + g*4 + r where
// the gate col cg = g*128 + (16w + 4q + r). Writers decode p -> source row.
__device__ __forceinline__ int ydecode(int p) {
    int pw = (p >> 6) & 7, pq = (p >> 4) & 3, pg = (p >> 2) & 3, pr = p & 3;
    return pg * 128 + pw * 16 + pq * 4 + pr;
}

// direct global->LDS DMA, 16B per lane (global_load_lds_dwordx4)
__device__ __forceinline__ void row_dma(const bf16* gp, void* lp) {
    __builtin_amdgcn_global_load_lds(
        (const __attribute__((address_space(1))) void*)gp,
        (__attribute__((address_space(3))) void*)lp, 16, 0, 0);
}

__global__ void detect_dtype(const unsigned short* __restrict__ xb, int* __restrict__ flag) {
    int cnt = 0;
    for (int i = threadIdx.x; i < 1024; i += 64) {
        int e = (xb[i] >> 7) & 0xFF;
        cnt += (e >= 0xC8);
    }
#pragma unroll
    for (int off = 32; off; off >>= 1) cnt += __shfl_down(cnt, off);
    if (threadIdx.x == 0) *flag = (cnt >= 16) ? 1 : 0;   // 1 => inputs are float32
}

struct Cvt { const void* src; bf16* dst; int n; };
struct CvtAll { Cvt t[19]; };

__global__ void convert_inputs(CvtAll ca, const int* __restrict__ flag) {
    const bool isf32 = (*flag != 0);
    const int stride = gridDim.x * blockDim.x;
    const int tid0 = blockIdx.x * blockDim.x + threadIdx.x;
#pragma unroll 1
    for (int k = 0; k < 19; k++) {
        const int n = ca.t[k].n;
        const float* sf = (const float*)ca.t[k].src;
        const bf16*  sb = (const bf16*)ca.t[k].src;
        bf16* d = ca.t[k].dst;
        for (int i = tid0; i < n; i += stride)
            d[i] = isf32 ? f2bf(sf[i]) : sb[i];
    }
}

// generic (final lin2 layer)
template <int NCT, bool RELU, bool BIAS2, bool DUAL, bool OUTF>
__global__ __launch_bounds__(256, 2) void gemm_bias(
    const bf16* __restrict__ A, const bf16* __restrict__ B,
    const bf16* __restrict__ bias, const bf16* __restrict__ bias2,
    const bf16* __restrict__ A2, const bf16* __restrict__ B2,
    void* __restrict__ Cv, const int* __restrict__ oflag,
    int N, int nbt, int ldc)
{
    const int tid = threadIdx.x;
    const int w = tid >> 6, l = tid & 63, q = l >> 4, lid = l & 15;
    const int rowbase = blockIdx.x * 64 + w * 16;
    const int colslice = blockIdx.y * (NCT * 16);

    int arow = rowbase + lid;
    if (arow >= N) arow = N - 1;

    floatx4 acc[NCT];
#pragma unroll
    for (int ct = 0; ct < NCT; ct++) acc[ct] = (floatx4)(0.f);

    short8 bfrag[NCT][4];
#pragma unroll
    for (int ct = 0; ct < NCT; ct++) {
        int j = colslice + ct * 16 + lid;
        if (j >= nbt) j = nbt - 1;
#pragma unroll
        for (int kt = 0; kt < 4; kt++)
            bfrag[ct][kt] = *(const short8*)(B + (size_t)j * 128 + kt * 32 + q * 8);
    }
#pragma unroll
    for (int kt = 0; kt < 4; kt++) {
        short8 af = *(const short8*)(A + (size_t)arow * 128 + kt * 32 + q * 8);
#pragma unroll
        for (int ct = 0; ct < NCT; ct++)
            acc[ct] = __builtin_amdgcn_mfma_f32_16x16x32_bf16(af, bfrag[ct][kt], acc[ct], 0, 0, 0);
    }
    if constexpr (DUAL) {
#pragma unroll
        for (int ct = 0; ct < NCT; ct++) {
            int j = colslice + ct * 16 + lid;
            if (j >= nbt) j = nbt - 1;
#pragma unroll
            for (int kt = 0; kt < 4; kt++)
                bfrag[ct][kt] = *(const short8*)(B2 + (size_t)j * 128 + kt * 32 + q * 8);
        }
#pragma unroll
        for (int kt = 0; kt < 4; kt++) {
            short8 af = *(const short8*)(A2 + (size_t)arow * 128 + kt * 32 + q * 8);
#pragma unroll
            for (int ct = 0; ct < NCT; ct++)
                acc[ct] = __builtin_amdgcn_mfma_f32_16x16x32_bf16(af, bfrag[ct][kt], acc[ct], 0, 0, 0);
        }
    }
    bool of32 = false;
    if constexpr (OUTF) of32 = (*oflag != 0);
#pragma unroll
    for (int ct = 0; ct < NCT; ct++) {
        int cg = colslice + ct * 16 + lid;
        int cb = cg < nbt ? cg : nbt - 1;
        float bv = bf2f(bias[cb]);
        if constexpr (BIAS2) bv += bf2f(bias2[cb]);
#pragma unroll
        for (int r = 0; r < 4; r++) {
            int row = rowbase + q * 4 + r;
            float v = acc[ct][r] + bv;
            if constexpr (RELU) v = fmaxf(v, 0.f);
            if (row < N && cg < nbt) {
                size_t idx = (size_t)row * ldc + cg;
                if constexpr (OUTF) {
                    if (of32) ((float*)Cv)[idx] = v;
                    else      ((bf16*)Cv)[idx] = f2bf(v);
                } else {
                    ((bf16*)Cv)[idx] = f2bf(v);
                }
            }
        }
    }
}

// ---------------------------------------------------------------------------
// Fused layer entry: Y = (relu(X@Wp^T+bp)) @ Wih^T + bih + bhh, permuted layout
// via SOURCE-ROW indexing: tile covers memory cols jm (contiguous stores);
// B-row loaded = Wih[ydecode(jm)], bias = (bih+bhh)[ydecode(jm)].
// ---------------------------------------------------------------------------
__global__ __launch_bounds__(256, 2) void fused_xp_y(
    const bf16* __restrict__ X, const bf16* __restrict__ Wp, const bf16* __restrict__ bp,
    const bf16* __restrict__ Wih, const bf16* __restrict__ bih, const bf16* __restrict__ bhh,
    bf16* __restrict__ Yout, int N)
{
    __shared__ bf16 T[64][136];
    const int tid = threadIdx.x;
    const int w = tid >> 6, l = tid & 63, q = l >> 4, lid = l & 15;
    const int rowbase = blockIdx.x * 64;

    int arow = rowbase + w * 16 + lid;
    if (arow >= N) arow = N - 1;

    floatx4 acc[8];
    short8 bfrag[8][4];

    // ---- stage A: xp = relu(X@Wp^T + bp) -> T ----
#pragma unroll
    for (int ct = 0; ct < 8; ct++) acc[ct] = (floatx4)(0.f);
#pragma unroll
    for (int ct = 0; ct < 8; ct++) {
        int j = ct * 16 + lid;
#pragma unroll
        for (int kt = 0; kt < 4; kt++)
            bfrag[ct][kt] = *(const short8*)(Wp + (size_t)j * 128 + kt * 32 + q * 8);
    }
#pragma unroll
    for (int kt = 0; kt < 4; kt++) {
        short8 af = *(const short8*)(X + (size_t)arow * 128 + kt * 32 + q * 8);
#pragma unroll
        for (int ct = 0; ct < 8; ct++)
            acc[ct] = __builtin_amdgcn_mfma_f32_16x16x32_bf16(af, bfrag[ct][kt], acc[ct], 0, 0, 0);
    }
#pragma unroll
    for (int ct = 0; ct < 8; ct++) {
        int col = ct * 16 + lid;
        float bv = bf2f(bp[col]);
#pragma unroll
        for (int r = 0; r < 4; r++)
            T[w * 16 + q * 4 + r][col] = f2bf(fmaxf(acc[ct][r] + bv, 0.f));
    }
    __syncthreads();

    // ---- stage B: Y chunks, contiguous stores, permute via source-row index ----
#pragma unroll 1
    for (int cc = 0; cc < 4; cc++) {
#pragma unroll
        for (int ct = 0; ct < 8; ct++) {
            int jm = cc * 128 + ct * 16 + lid;      // memory column
            int src = ydecode(jm);                  // source gate row
#pragma unroll
            for (int kt = 0; kt < 4; kt++)
                bfrag[ct][kt] = *(const short8*)(Wih + (size_t)src * 128 + kt * 32 + q * 8);
        }
#pragma unroll
        for (int ct = 0; ct < 8; ct++) acc[ct] = (floatx4)(0.f);
#pragma unroll
        for (int kt = 0; kt < 4; kt++) {
            short8 af = *(const short8*)&T[w * 16 + lid][kt * 32 + q * 8];
#pragma unroll
            for (int ct = 0; ct < 8; ct++)
                acc[ct] = __builtin_amdgcn_mfma_f32_16x16x32_bf16(af, bfrag[ct][kt], acc[ct], 0, 0, 0);
        }
#pragma unroll
        for (int ct = 0; ct < 8; ct++) {
            int jm = cc * 128 + ct * 16 + lid;
            int src = ydecode(jm);
            float bv = bf2f(bih[src]) + bf2f(bhh[src]);
#pragma unroll
            for (int r = 0; r < 4; r++) {
                int row = rowbase + w * 16 + q * 4 + r;
                if (row < N) Yout[(size_t)row * 512 + jm] = f2bf(acc[ct][r] + bv);
            }
        }
    }
}

// ---------------------------------------------------------------------------
// Fused between-layers: h1 = relu(aggr@Wl^T+bl+X@Wr^T) (global+LDS);
// xp2 = relu(h1@Wp2^T+bp2) (LDS); Y2 = permuted via source-row indexing.
// ---------------------------------------------------------------------------
__global__ __launch_bounds__(256, 2) void fused_lin_xp_y(
    const bf16* __restrict__ aggr, const bf16* __restrict__ Wl, const bf16* __restrict__ bl,
    const bf16* __restrict__ X, const bf16* __restrict__ Wr,
    bf16* __restrict__ h1out,
    const bf16* __restrict__ Wp2, const bf16* __restrict__ bp2,
    const bf16* __restrict__ Wih2, const bf16* __restrict__ bih2, const bf16* __restrict__ bhh2,
    bf16* __restrict__ Yout, int N)
{
    __shared__ bf16 T1[64][136];
    __shared__ bf16 T2[64][136];
    const int tid = threadIdx.x;
    const int w = tid >> 6, l = tid & 63, q = l >> 4, lid = l & 15;
    const int rowbase = blockIdx.x * 64;

    int arow = rowbase + w * 16 + lid;
    if (arow >= N) arow = N - 1;

    floatx4 acc[8];
    short8 bfrag[8][4];

    // ---- stage A: h1 ----
#pragma unroll
    for (int ct = 0; ct < 8; ct++) acc[ct] = (floatx4)(0.f);
#pragma unroll
    for (int ct = 0; ct < 8; ct++) {
        int j = ct * 16 + lid;
#pragma unroll
        for (int kt = 0; kt < 4; kt++)
            bfrag[ct][kt] = *(const short8*)(Wl + (size_t)j * 128 + kt * 32 + q * 8);
    }
#pragma unroll
    for (int kt = 0; kt < 4; kt++) {
        short8 af = *(const short8*)(aggr + (size_t)arow * 128 + kt * 32 + q * 8);
#pragma unroll
        for (int ct = 0; ct < 8; ct++)
            acc[ct] = __builtin_amdgcn_mfma_f32_16x16x32_bf16(af, bfrag[ct][kt], acc[ct], 0, 0, 0);
    }
#pragma unroll
    for (int ct = 0; ct < 8; ct++) {
        int j = ct * 16 + lid;
#pragma unroll
        for (int kt = 0; kt < 4; kt++)
            bfrag[ct][kt] = *(const short8*)(Wr + (size_t)j * 128 + kt * 32 + q * 8);
    }
#pragma unroll
    for (int kt = 0; kt < 4; kt++) {
        short8 af = *(const short8*)(X + (size_t)arow * 128 + kt * 32 + q * 8);
#pragma unroll
        for (int ct = 0; ct < 8; ct++)
            acc[ct] = __builtin_amdgcn_mfma_f32_16x16x32_bf16(af, bfrag[ct][kt], acc[ct], 0, 0, 0);
    }
#pragma unroll
    for (int ct = 0; ct < 8; ct++) {
        int col = ct * 16 + lid;
        float bv = bf2f(bl[col]);
#pragma unroll
        for (int r = 0; r < 4; r++) {
            int rl = w * 16 + q * 4 + r;
            bf16 hv = f2bf(fmaxf(acc[ct][r] + bv, 0.f));
            T1[rl][col] = hv;
            int row = rowbase + rl;
            if (row < N) h1out[(size_t)row * 128 + col] = hv;
        }
    }
    __syncthreads();

    // ---- stage B: xp2 -> T2 ----
#pragma unroll
    for (int ct = 0; ct < 8; ct++) {
        int j = ct * 16 + lid;
#pragma unroll
        for (int kt = 0; kt < 4; kt++)
            bfrag[ct][kt] = *(const short8*)(Wp2 + (size_t)j * 128 + kt * 32 + q * 8);
    }
#pragma unroll
    for (int ct = 0; ct < 8; ct++) acc[ct] = (floatx4)(0.f);
#pragma unroll
    for (int kt = 0; kt < 4; kt++) {
        short8 af = *(const short8*)&T1[w * 16 + lid][kt * 32 + q * 8];
#pragma unroll
        for (int ct = 0; ct < 8; ct++)
            acc[ct] = __builtin_amdgcn_mfma_f32_16x16x32_bf16(af, bfrag[ct][kt], acc[ct], 0, 0, 0);
    }
#pragma unroll
    for (int ct = 0; ct < 8; ct++) {
        int col = ct * 16 + lid;
        float bv = bf2f(bp2[col]);
#pragma unroll
        for (int r = 0; r < 4; r++)
            T2[w * 16 + q * 4 + r][col] = f2bf(fmaxf(acc[ct][r] + bv, 0.f));
    }
    __syncthreads();

    // ---- stage C: Y2 chunks, contiguous stores, permute via source-row index ----
#pragma unroll 1
    for (int cc = 0; cc < 4; cc++) {
#pragma unroll
        for (int ct = 0; ct < 8; ct++) {
            int jm = cc * 128 + ct * 16 + lid;
            int src = ydecode(jm);
#pragma unroll
            for (int kt = 0; kt < 4; kt++)
                bfrag[ct][kt] = *(const short8*)(Wih2 + (size_t)src * 128 + kt * 32 + q * 8);
        }
#pragma unroll
        for (int ct = 0; ct < 8; ct++) acc[ct] = (floatx4)(0.f);
#pragma unroll
        for (int kt = 0; kt < 4; kt++) {
            short8 af = *(const short8*)&T2[w * 16 + lid][kt * 32 + q * 8];
#pragma unroll
            for (int ct = 0; ct < 8; ct++)
                acc[ct] = __builtin_amdgcn_mfma_f32_16x16x32_bf16(af, bfrag[ct][kt], acc[ct], 0, 0, 0);
        }
#pragma unroll
        for (int ct = 0; ct < 8; ct++) {
            int jm = cc * 128 + ct * 16 + lid;
            int src = ydecode(jm);
            float bv = bf2f(bih2[src]) + bf2f(bhh2[src]);
#pragma unroll
            for (int r = 0; r < 4; r++) {
                int row = rowbase + w * 16 + q * 4 + r;
                if (row < N) Yout[(size_t)row * 512 + jm] = f2bf(acc[ct][r] + bv);
            }
        }
    }
}

// ---------------------------------------------------------------------------
// LSTM neighbor aggregation (r10-exact: the measured plateau optimum).
// 512 thr / 8 waves / 16 nodes; wave w owns hidden cols [16w,16w+16).
// Per step: wave w DMAs Y rows {2w,2w+1} (1KB) into stage; thread reads its 16
// gate-values as 2 contiguous ds_read_b128; 4 cells/thread; __syncthreads.
// ---------------------------------------------------------------------------
__global__ __launch_bounds__(512, 4) void lstm_aggr(
    const bf16* __restrict__ Y,     // [N,512] PERMUTED pre-activations
    const int* __restrict__ esrc,   // [N,16]
    const bf16* __restrict__ Whh,   // [512,128]
    bf16* __restrict__ aggr,        // [N,128] out: final h
    int N)
{
    __shared__ alignas(16) short stage[2][16][520];  // 1040B row stride
    __shared__ alignas(16) bf16 hb[2][16][136];
    __shared__ int srcl[16][16];    // [t][node]

    const int tid = threadIdx.x;
    const int w = tid >> 6, l = tid & 63, q = l >> 4, lid = l & 15;
    const int nodebase = blockIdx.x * 16;   // N = 50000 = 3125*16, exact

    if (tid < 256) {
        int node = tid >> 4, t = tid & 15;
        srcl[t][node] = esrc[(size_t)(nodebase + node) * 16 + t];
    }
    for (int i = tid; i < 16 * 136; i += 512) ((short*)hb[0])[i] = 0;

    // Whh A-fragments: wf[g][kt]; A-row = gatecol = g*128 + 16*w + lid
    short8 wf[4][4];
#pragma unroll
    for (int g = 0; g < 4; g++) {
        int gc = g * 128 + 16 * w + lid;
#pragma unroll
        for (int kt = 0; kt < 4; kt++)
            wf[g][kt] = *(const short8*)(Whh + (size_t)gc * 128 + kt * 32 + q * 8);
    }

    float c[4];
#pragma unroll
    for (int r = 0; r < 4; r++) c[r] = 0.f;

    __syncthreads();   // srcl visible before first DMA

#pragma unroll
    for (int j = 0; j < 2; j++) {
        int r = 2 * w + j;
        int s = srcl[0][r];
        row_dma(Y + (size_t)s * 512 + l * 8, &stage[0][r][0]);
    }
    __syncthreads();   // drains vmcnt: stage[0] landed

#pragma unroll 2
    for (int t = 0; t < 16; t++) {
        const int cb = t & 1, nb = cb ^ 1;

        if (t < 15) {
#pragma unroll
            for (int j = 0; j < 2; j++) {
                int r = 2 * w + j;
                int s = srcl[t + 1][r];
                row_dma(Y + (size_t)s * 512 + l * 8, &stage[nb][r][0]);
            }
        }

        floatx4 acc[4];
        {
            short8 y0 = *(const short8*)&stage[cb][lid][w * 64 + q * 16];
            short8 y1 = *(const short8*)&stage[cb][lid][w * 64 + q * 16 + 8];
#pragma unroll
            for (int g = 0; g < 2; g++)
#pragma unroll
                for (int r = 0; r < 4; r++) {
                    acc[g][r]     = bfs2f(y0[g * 4 + r]);
                    acc[2 + g][r] = bfs2f(y1[g * 4 + r]);
                }
        }

#pragma unroll
        for (int kt = 0; kt < 4; kt++) {
            short8 bh = *(const short8*)&hb[cb][lid][kt * 32 + q * 8];
#pragma unroll
            for (int g = 0; g < 4; g++)
                acc[g] = __builtin_amdgcn_mfma_f32_16x16x32_bf16(wf[g][kt], bh, acc[g], 0, 0, 0);
        }

        {
            short4v hv;
#pragma unroll
            for (int r = 0; r < 4; r++)
                hv[r] = f2bfs(cell(acc[0][r], acc[1][r], acc[2][r], acc[3][r], c[r]));
            if (t < 15) *(short4v*)&hb[nb][lid][16 * w + 4 * q] = hv;
            else        *(short4v*)(aggr + (size_t)(nodebase + lid) * 128 + 16 * w + 4 * q) = hv;
        }

        __syncthreads();
    }
}

extern "C" void kernel_launch(void* const* d_in, const int* in_sizes, int n_in,
                              void* d_out, int out_size, void* d_ws, size_t ws_size,
                              hipStream_t stream)
{
    const int N = 50000;
    const int* es = (const int*)d_in[1];
    char* ws = (char*)d_ws;

    // converted bf16 copies of the 19 used float tensors @[0,15MB)
    static const int idxs[19] = {0, 8,9,10,11,12,13,14,15,16, 17,18,19,20,21,22,23,24,25};
    bf16* conv[19];
    size_t off = 0;
    CvtAll ca;
    for (int k = 0; k < 19; k++) {
        conv[k] = (bf16*)ws + off;
        ca.t[k].src = d_in[idxs[k]];
        ca.t[k].dst = conv[k];
        ca.t[k].n = in_sizes[idxs[k]];
        off += (size_t)((in_sizes[idxs[k]] + 63) & ~63);
    }
    int* flag = (int*)(ws + ((size_t)15 << 20));
    bf16* aggr = (bf16*)(ws + ((size_t)16 << 20));   // [N,128]
    bf16* Y    = (bf16*)(ws + ((size_t)30 << 20));   // [N,512] permuted
    bf16* h1   = (bf16*)(ws + ((size_t)84 << 20));   // [N,128]

    const bf16 *xc  = conv[0];
    const bf16 *Wp1 = conv[1],  *bp1 = conv[2],  *Wih1 = conv[3],  *Whh1 = conv[4];
    const bf16 *bih1 = conv[5], *bhh1 = conv[6], *Wl1 = conv[7],   *bl1 = conv[8],  *Wr1 = conv[9];
    const bf16 *Wp2 = conv[10], *bp2 = conv[11], *Wih2 = conv[12], *Whh2 = conv[13];
    const bf16 *bih2 = conv[14], *bhh2 = conv[15], *Wl2 = conv[16], *bl2 = conv[17], *Wr2 = conv[18];

    dim3 blk(256);
    const int gx = (N + 63) / 64;    // 782
    const int gl = N / 16;           // 3125 (exact)

    detect_dtype<<<dim3(1), dim3(64), 0, stream>>>((const unsigned short*)d_in[0], flag);
    convert_inputs<<<dim3(1024), blk, 0, stream>>>(ca, flag);

    // ---- layer 1 ----
    fused_xp_y<<<dim3(gx), blk, 0, stream>>>(xc, Wp1, bp1, Wih1, bih1, bhh1, Y, N);
    lstm_aggr<<<dim3(gl), dim3(512), 0, stream>>>(Y, es, Whh1, aggr, N);

    // ---- between layers: lin1 -> xp2 -> Y2 ----
    fused_lin_xp_y<<<dim3(gx), blk, 0, stream>>>(
        aggr, Wl1, bl1, xc, Wr1, h1, Wp2, bp2, Wih2, bih2, bhh2, Y, N);
    lstm_aggr<<<dim3(gl), dim3(512), 0, stream>>>(Y, es, Whh2, aggr, N);

    // ---- final: out = lin_l2(aggr) + bl2 + lin_r2(h1) ----
    gemm_bias<3, false, false, true, true><<<dim3(gx, 1), blk, 0, stream>>>(
        aggr, Wl2, bl2, nullptr, h1, Wr2, d_out, flag, N, 40, 40);
}